// Round 13
// baseline (37.535 us; speedup 1.0000x reference)
//
#include <hip/hip_runtime.h>
#include <math.h>

#define OUT 14
#define RATIO 2
#define NS (OUT*RATIO)      // 28 sample positions per axis
#define NPIX (OUT*OUT)      // 196
#define C_TOT 256
#define CG 4                // channels per group (float4 interleave)
#define GPB 4               // groups per block (prologue amortization)
#define NCHUNK (C_TOT/(CG*GPB))   // 16
#define NBOX_PER_B 128
#define NTHREADS 256
#define PATCH_CAP 1280      // float4 slots; worst swizzled patch ~1230
#define MAXIT 5             // ceil(PATCH_CAP/NTHREADS)
#define NROI 256

// ---------------------------------------------------------------------
// torchvision roi_align axis prep (must match reference op-for-op):
// valid = (c>-1)&(c<L); c=clip(c,0,L-1); lo=clip(floor(c),0,L-2); fr=c-lo
// ---------------------------------------------------------------------
__device__ __forceinline__ void prep_axis(float c, int L, int& lo, float& fh, float& fl)
{
    const bool  v  = (c > -1.0f) && (c < (float)L);
    const float cc = fminf(fmaxf(c, 0.0f), (float)(L - 1));
    const float fb = fminf(fmaxf(floorf(cc), 0.0f), (float)(L - 2));
    const float fr = cc - fb;
    lo = (int)fb;
    fl = v ? fr        : 0.0f;
    fh = v ? 1.0f - fr : 0.0f;
}

__device__ __forceinline__ int axis_lo(float c, int L)
{
    const float cc = fminf(fmaxf(c, 0.0f), (float)(L - 1));
    return (int)fminf(fmaxf(floorf(cc), 0.0f), (float)(L - 2));
}

// =====================================================================
// R12 structure (GPB=4, fused, amortized prologue) + bank-conflict
// skip-swizzle on the patch column index: slot(c) = c + (c>>3).
// Lane strides of 2 mod 8 (large/elongated rois) previously aliased to
// the same 4-bank group on ds_read_b128; the swizzle breaks the mod-8
// alias. Guarded fallback to identity layout if the padded patch
// exceeds PATCH_CAP (rare; those shapes are narrow and conflict-free).
// =====================================================================
__global__ __launch_bounds__(NTHREADS)
void roi_align_fused4s_kernel(const float* __restrict__ f0,
                              const float* __restrict__ f1,
                              const float* __restrict__ f2,
                              const float* __restrict__ f3,
                              const float* __restrict__ boxes,
                              float* __restrict__ out)
{
    const int chunk = blockIdx.x;   // 0..15
    const int k     = blockIdx.y;   // roi, 0..255
    const int tid   = threadIdx.x;

    __shared__ float4 s_patch[PATCH_CAP];   // 20480 B exactly

    // ---- per-roi params (uniform; computed redundantly, no LDS) ----
    const float bx1 = boxes[k*4+0];
    const float by1 = boxes[k*4+1];
    const float bx2 = boxes[k*4+2];
    const float by2 = boxes[k*4+3];

    const float wbox = bx2 - bx1;
    const float hbox = by2 - by1;
    const float sdim = sqrtf(wbox * hbox);
    float lvlf = floorf(4.0f + log2f(sdim / 224.0f + 1e-6f));
    lvlf = fminf(fmaxf(lvlf, 2.0f), 5.0f);
    const int lidx = (int)lvlf - 2;   // 0..3

    const float* fptr;
    int H, W;
    float scale;
    if      (lidx == 0) { fptr = f0; H = 200; W = 200; scale = 0.25f;    }
    else if (lidx == 1) { fptr = f1; H = 100; W = 100; scale = 0.125f;   }
    else if (lidx == 2) { fptr = f2; H = 50;  W = 50;  scale = 0.0625f;  }
    else                { fptr = f3; H = 25;  W = 25;  scale = 0.03125f; }

    const float x1 = bx1 * scale;
    const float y1 = by1 * scale;
    const float x2 = bx2 * scale;
    const float y2 = by2 * scale;
    const float rw = fmaxf(x2 - x1, 1.0f);
    const float rh = fmaxf(y2 - y1, 1.0f);
    const float bw = rw / (float)OUT;
    const float bh = rh / (float)OUT;

    // ---- patch extent from first/last sample (monotone tables) ----
    const float off0  = 0.25f;
    const float offL  = ((float)(NS-1) + 0.5f) * 0.5f;
    const int ymin  = axis_lo(y1 + bh * off0, H);
    const int xmin  = axis_lo(x1 + bw * off0, W);
    const int nrows = axis_lo(y1 + bh * offL, H) + 2 - ymin;
    const int ncols = axis_lo(x1 + bw * offL, W) + 2 - xmin;

    // ---- swizzled layout: slot(c) = c + (c>>3) when it fits ----
    const int swzw   = (ncols - 1) + ((ncols - 1) >> 3) + 1;   // swizzled row width
    const int strideS = swzw | 1;
    const int strideP = ncols | 1;
    const bool useswz = (nrows * strideS <= PATCH_CAP);
    const int stridep = useswz ? strideS
                               : ((nrows * strideP <= PATCH_CAP) ? strideP : ncols);
    const int swsh    = useswz ? 3 : 31;    // c + (c >> swsh); >>31 == +0 for c>=0
    const int nelem   = nrows * ncols;
    const float rcpc  = 1.0f / (float)ncols;

    // ---- per-pixel tap state in registers (computed once) ----
    const bool active = (tid < NPIX);
    int rb0 = 0, rb1 = 0;
    int cb0a = 0, cb0b = 0, cb1a = 0, cb1b = 0;   // swizzled col slots for 4 x-taps
    float4 wy = {0,0,0,0};   // y weights * 0.25
    float4 wx = {0,0,0,0};   // x weights
    if (active) {
        const int ph = tid / OUT;
        const int pw = tid - ph * OUT;
        int lo; float fh, fl;
        prep_axis(y1 + bh * (((float)(2*ph)   + 0.5f) * 0.5f), H, lo, fh, fl);
        rb0 = (lo - ymin) * stridep; wy.x = fh * 0.25f; wy.y = fl * 0.25f;
        prep_axis(y1 + bh * (((float)(2*ph+1) + 0.5f) * 0.5f), H, lo, fh, fl);
        rb1 = (lo - ymin) * stridep; wy.z = fh * 0.25f; wy.w = fl * 0.25f;
        prep_axis(x1 + bw * (((float)(2*pw)   + 0.5f) * 0.5f), W, lo, fh, fl);
        {
            const int c = lo - xmin;
            cb0a = c + (c >> swsh);
            cb0b = (c + 1) + ((c + 1) >> swsh);
            wx.x = fh; wx.y = fl;
        }
        prep_axis(x1 + bw * (((float)(2*pw+1) + 0.5f) * 0.5f), W, lo, fh, fl);
        {
            const int c = lo - xmin;
            cb1a = c + (c >> swsh);
            cb1b = (c + 1) + ((c + 1) >> swsh);
            wx.z = fh; wx.w = fl;
        }
    }

    // ---- staging coordinates (computed once, reused for all groups) ----
    const size_t plane = (size_t)H * (size_t)W;
    int go_[MAXIT], di_[MAXIT];
    #pragma unroll
    for (int t = 0; t < MAXIT; ++t) {
        const int i  = t*NTHREADS + tid;
        const int r  = (int)(((float)i + 0.5f) * rcpc);   // exact floor
        const int cc = i - r * ncols;
        const int di = r * stridep + cc + (cc >> swsh);
        go_[t] = r * W + cc;
        di_[t] = (i < nelem && di < PATCH_CAP) ? di : -1;
    }

    const float* fbase = fptr
        + ((size_t)(k / NBOX_PER_B) * C_TOT + (size_t)chunk * (GPB*CG)) * plane
        + (size_t)ymin * W + xmin;
    float* outk = out + ((size_t)k * C_TOT + (size_t)chunk * (GPB*CG)) * NPIX;

    #pragma unroll
    for (int g = 0; g < GPB; ++g) {
        // ---- stage group g: 4 channels interleaved, coalesced ----
        const float* g0 = fbase + (size_t)(g*CG) * plane;
        const float* g1 = g0 +   plane;
        const float* g2 = g0 + 2*plane;
        const float* g3 = g0 + 3*plane;
        #pragma unroll
        for (int t = 0; t < MAXIT; ++t) {
            if (di_[t] >= 0) {
                const int go = go_[t];
                float4 v;
                v.x = g0[go]; v.y = g1[go]; v.z = g2[go]; v.w = g3[go];
                s_patch[di_[t]] = v;
            }
        }
        __syncthreads();

        // ---- bilinear: 16 x ds_read_b128, 64 FMA per pixel ----
        if (active) {
            float4 acc = {0.0f, 0.0f, 0.0f, 0.0f};
            #pragma unroll
            for (int ys = 0; ys < 2; ++ys) {
                const int   rb = ys ? rb1 : rb0;
                const float yh = ys ? wy.z : wy.x;
                const float yl = ys ? wy.w : wy.y;
                #pragma unroll
                for (int xs = 0; xs < 2; ++xs) {
                    const int ca = rb + (xs ? cb1a : cb0a);
                    const int cb = rb + (xs ? cb1b : cb0b);
                    const float xh = xs ? wx.z : wx.x;
                    const float xl = xs ? wx.w : wx.y;
                    const float w00 = yh*xh, w01 = yh*xl, w10 = yl*xh, w11 = yl*xl;
                    const float4 v00 = s_patch[ca];
                    const float4 v01 = s_patch[cb];
                    const float4 v10 = s_patch[ca + stridep];
                    const float4 v11 = s_patch[cb + stridep];
                    acc.x += w00*v00.x + w01*v01.x + w10*v10.x + w11*v11.x;
                    acc.y += w00*v00.y + w01*v01.y + w10*v10.y + w11*v11.y;
                    acc.z += w00*v00.z + w01*v01.z + w10*v10.z + w11*v11.z;
                    acc.w += w00*v00.w + w01*v01.w + w10*v10.w + w11*v11.w;
                }
            }
            float* ob = outk + (size_t)(g*CG) * NPIX + tid;
            ob[0*NPIX] = acc.x;
            ob[1*NPIX] = acc.y;
            ob[2*NPIX] = acc.z;
            ob[3*NPIX] = acc.w;
        }
        if (g + 1 < GPB) __syncthreads();
    }
}

extern "C" void kernel_launch(void* const* d_in, const int* in_sizes, int n_in,
                              void* d_out, int out_size, void* d_ws, size_t ws_size,
                              hipStream_t stream) {
    const float* f0    = (const float*)d_in[0];
    const float* f1    = (const float*)d_in[1];
    const float* f2    = (const float*)d_in[2];
    const float* f3    = (const float*)d_in[3];
    const float* boxes = (const float*)d_in[4];
    float* out = (float*)d_out;

    dim3 grid(NCHUNK, NROI);   // 16 chunks x 256 rois (same-roi adjacent)
    roi_align_fused4s_kernel<<<grid, NTHREADS, 0, stream>>>(f0, f1, f2, f3, boxes, out);
}